// Round 14
// baseline (112.321 us; speedup 1.0000x reference)
//
#include <hip/hip_runtime.h>
#include <hip/hip_bf16.h>

// RGCN CSR, two layers, MI355X.  Transform-then-gather, separate kernels.
//   xw1[n][512] = x @ W1flat     (K=64 bf16 MFMA, fused f32 cast, B in LDS)
//   h[n][64]    = relu(gather(xw1))          <- k_gs_relu
//   xw2[n][320] = h @ W2flat                 <- k_xw2, B in LDS
//   out[n][40]  = log_softmax(gather(xw2))   <- k_gs_lsm
// R14: gather ILP x2 inside the PROVEN 2-row shape — each wave handles 4 rows
// as two sequential pairs; all 32 loads issued before any accumulate (one
// latency exposure per 4 rows instead of 2). Lane map (fl=lane&31, eo),
// dword loads, eo-select, per-pair stores, generic fallback: identical to the
// 3-round-proven R13 code. (R12's failed widening changed lane map + load
// width + select depth at once; this isolates load-batch depth only.)

typedef __attribute__((ext_vector_type(8))) short short8;
typedef __attribute__((ext_vector_type(4))) float floatx4;

static __device__ __forceinline__ unsigned short f2bf(float f) {
    unsigned u = __float_as_uint(f);
    u += 0x7FFFu + ((u >> 16) & 1u);      // RNE
    return (unsigned short)(u >> 16);
}
static __device__ __forceinline__ float bflo(unsigned u) { return __uint_as_float(u << 16); }
static __device__ __forceinline__ float bfhi(unsigned u) { return __uint_as_float(u & 0xffff0000u); }

// sigma: within-slab col interleave, involution on [0,64)
static __device__ __forceinline__ int sgm(int d) {
    return ((d & 12) << 2) | ((d & 48) >> 2) | (d & 3);
}

// ---- pack weights into fragment-linear BTf ----
// chunk = (cb*2+k0)*4+g (1KB each); within chunk, lane=lg*16+lr holds 8 shorts:
//   BTf[chunk*512 + lg*128 + lr*8 + s] = B[cb*64+g*16+lr][k0*32+lg*8+s]
// Layer1: B[j][d] = W1[r][d][f], j=r*64+f.       (8 slabs, 32768 shorts)
// Layer2: B[j][d] = W2[r][sgm(d)][f], j=r*40+f.  (5 slabs, 20480 shorts)
__global__ void k_packw(const float* __restrict__ W1, const float* __restrict__ W2,
                        unsigned short* __restrict__ BTf1, unsigned short* __restrict__ BTf2) {
    int i = blockIdx.x * 256 + threadIdx.x;
    if (i < 32768) {
        int chunk = i >> 9, w = i & 511;
        int cb = chunk >> 3, k0 = (chunk >> 2) & 1, g = chunk & 3;
        int lg = w >> 7, lr = (w >> 3) & 15, s = w & 7;
        int j = cb * 64 + g * 16 + lr;
        int d = k0 * 32 + lg * 8 + s;
        int r = j >> 6, f = j & 63;
        BTf1[i] = f2bf(W1[r * 4096 + d * 64 + f]);
    } else if (i < 32768 + 20480) {
        int ii = i - 32768;
        int chunk = ii >> 9, w = ii & 511;
        int cb = chunk >> 3, k0 = (chunk >> 2) & 1, g = chunk & 3;
        int lg = w >> 7, lr = (w >> 3) & 15, s = w & 7;
        int j = cb * 64 + g * 16 + lr;                 // < 320
        int d = k0 * 32 + lg * 8 + s;
        int r = j / 40, f = j - r * 40;
        BTf2[ii] = f2bf(W2[r * 2560 + sgm(d) * 40 + f]);
    }
}

// ---- dense GEMM: xw[MP][NC] = A[MP][64] @ B^T  (K=64, bf16 MFMA, B in LDS) ----
// AF32=1: A f32 (x), rows>=M read 0 (fused cast), sigma-phys output, 2x16B stores.
// AF32=0: A bf16 (h phys), logical output, 8B stores.
// Wave owns 16 rows; operand-swapped MFMA: acc[g] = 4 consecutive cols of one row.
template <int AF32, int NSLAB>
__global__ __launch_bounds__(256) void k_xw(
    const void* __restrict__ Av, const unsigned short* __restrict__ BTf,
    unsigned short* __restrict__ xw, int M) {
    constexpr int NC = NSLAB * 64;
    __shared__ short Bs[NSLAB * 4096];       // NSLAB*8KB

    // stage BTf -> LDS (coalesced, once per block)
#pragma unroll
    for (int off = 0; off < NSLAB * 4096; off += 2048)
        *(short8*)(Bs + off + threadIdx.x * 8) =
            *(const short8*)((const short*)BTf + off + threadIdx.x * 8);

    int wave = threadIdx.x >> 6, lane = threadIdx.x & 63;
    int lr = lane & 15, lg = lane >> 4;
    int rowbase = (blockIdx.x * 4 + wave) * 16;
    int row = rowbase + lr;

    short8 af[2];                             // [k0] — A read exactly once
#pragma unroll
    for (int k0 = 0; k0 < 2; ++k0) {
        int koff = k0 * 32 + lg * 8;
        if constexpr (AF32) {
            const float* Af = (const float*)Av;
            float4 v0 = {0, 0, 0, 0}, v1 = {0, 0, 0, 0};
            if (row < M) {
                v0 = *(const float4*)(Af + (size_t)row * 64 + koff);
                v1 = *(const float4*)(Af + (size_t)row * 64 + koff + 4);
            }
            short8 t;
            t[0] = (short)f2bf(v0.x); t[1] = (short)f2bf(v0.y);
            t[2] = (short)f2bf(v0.z); t[3] = (short)f2bf(v0.w);
            t[4] = (short)f2bf(v1.x); t[5] = (short)f2bf(v1.y);
            t[6] = (short)f2bf(v1.z); t[7] = (short)f2bf(v1.w);
            af[k0] = t;
        } else {
            const unsigned short* Ab = (const unsigned short*)Av;
            af[k0] = *(const short8*)(Ab + (size_t)row * 64 + koff);
        }
    }

    __syncthreads();                          // LDS B ready

#pragma unroll
    for (int cb = 0; cb < NSLAB; ++cb) {
        int col0 = cb * 64;
        floatx4 acc[4] = {};
#pragma unroll
        for (int k0 = 0; k0 < 2; ++k0) {
#pragma unroll
            for (int g = 0; g < 4; ++g) {
                short8 b = *(const short8*)(Bs + ((cb * 2 + k0) * 4 + g) * 512 + lane * 8);
                acc[g] = __builtin_amdgcn_mfma_f32_16x16x32_bf16(b, af[k0], acc[g], 0, 0, 0);
            }
        }
        // thread holds row=rowbase+lr, logical cols col0 + g*16 + lg*4 + i
        if constexpr (AF32) {
            // sigma-phys: within-slab phys col = lg*16 + g*4 + i -> 16 contiguous
            short8 o0, o1;
#pragma unroll
            for (int g = 0; g < 2; ++g)
#pragma unroll
                for (int i = 0; i < 4; ++i) {
                    o0[g * 4 + i] = (short)f2bf(acc[g][i]);
                    o1[g * 4 + i] = (short)f2bf(acc[g + 2][i]);
                }
            unsigned short* p = xw + (size_t)row * NC + col0 + lg * 16;
            *(short8*)p = o0;
            *(short8*)(p + 8) = o1;
        } else {
#pragma unroll
            for (int g = 0; g < 4; ++g) {
                unsigned lo = ((unsigned)f2bf(acc[g][1]) << 16) | f2bf(acc[g][0]);
                unsigned hi = ((unsigned)f2bf(acc[g][3]) << 16) | f2bf(acc[g][2]);
                uint2 o = {lo, hi};
                *(uint2*)(xw + (size_t)row * NC + col0 + g * 16 + lg * 4) = o;
            }
        }
    }
}

// ---- gather-sum + relu -> h bf16 [MP][64] (phys layout); zero pad rows ----
// 4 rows/wave as TWO pairs (proven 2-row shape); 32 loads in flight.
__global__ __launch_bounds__(256) void k_gs_relu(
    const unsigned short* __restrict__ xw,   // [(n*8+r)][64] phys, 128B rows
    const int* __restrict__ ptr, const int* __restrict__ idx,
    const int* __restrict__ rel,
    unsigned short* __restrict__ H, int M, int MP) {
    int base = (blockIdx.x * 4 + (threadIdx.x >> 6)) * 4;
    if (base >= MP) return;
    base = __builtin_amdgcn_readfirstlane(base);
    int lane = threadIdx.x & 63;
    int fl = lane & 31, eo = lane >> 5;
    int row1 = base + eo;                    // pair-1 row owned by this half-wave
    int row2 = base + 2 + eo;                // pair-2 row
    if (base >= M) {                         // all-pad quad -> zeros
        *(unsigned*)(H + (size_t)row1 * 64 + fl * 2) = 0;
        *(unsigned*)(H + (size_t)row2 * 64 + fl * 2) = 0;
        return;
    }
    float cx1 = 0.f, cy1 = 0.f, cx2 = 0.f, cy2 = 0.f;
    bool fast4 = false;
    if (base + 3 < M) {
        int p0 = ptr[base], p1 = ptr[base + 1], p2 = ptr[base + 2];
        int p3 = ptr[base + 3], p4 = ptr[base + 4];
        if ((p1 - p0) == 16 && (p2 - p1) == 16 && (p3 - p2) == 16 && (p4 - p3) == 16) {
            fast4 = true;
            const int* ia = idx + p0; const int* ra = rel + p0;   // 64 contiguous scalars
            unsigned u1[16], u2[16];
#pragma unroll
            for (int t = 0; t < 16; ++t) {
                unsigned bA = ((unsigned)ia[t]      * 8u + (unsigned)ra[t])      * 128u;
                unsigned bB = ((unsigned)ia[16 + t] * 8u + (unsigned)ra[16 + t]) * 128u;
                unsigned b = eo ? bB : bA;
                u1[t] = *(const unsigned*)((const char*)xw + b + fl * 4);
            }
#pragma unroll
            for (int t = 0; t < 16; ++t) {
                unsigned bC = ((unsigned)ia[32 + t] * 8u + (unsigned)ra[32 + t]) * 128u;
                unsigned bD = ((unsigned)ia[48 + t] * 8u + (unsigned)ra[48 + t]) * 128u;
                unsigned b = eo ? bD : bC;
                u2[t] = *(const unsigned*)((const char*)xw + b + fl * 4);
            }
#pragma unroll
            for (int t = 0; t < 16; ++t) { cx1 += bflo(u1[t]); cy1 += bfhi(u1[t]); }
#pragma unroll
            for (int t = 0; t < 16; ++t) { cx2 += bflo(u2[t]); cy2 += bfhi(u2[t]); }
        }
    }
    if (!fast4) {                             // generic per-row (proven loop)
        if (row1 < M) {
            int ps = ptr[row1], deg = ptr[row1 + 1] - ps;
            for (int t = 0; t < deg; ++t) {
                unsigned b = ((unsigned)idx[ps + t] * 8u + (unsigned)rel[ps + t]) * 128u;
                unsigned u = *(const unsigned*)((const char*)xw + b + fl * 4);
                cx1 += bflo(u); cy1 += bfhi(u);
            }
        }
        if (row2 < M) {
            int ps = ptr[row2], deg = ptr[row2 + 1] - ps;
            for (int t = 0; t < deg; ++t) {
                unsigned b = ((unsigned)idx[ps + t] * 8u + (unsigned)rel[ps + t]) * 128u;
                unsigned u = *(const unsigned*)((const char*)xw + b + fl * 4);
                cx2 += bflo(u); cy2 += bfhi(u);
            }
        }
    }
    unsigned o1 = ((unsigned)f2bf(fmaxf(cy1, 0.f)) << 16) | f2bf(fmaxf(cx1, 0.f));
    *(unsigned*)(H + (size_t)row1 * 64 + fl * 2) = o1;
    unsigned o2 = ((unsigned)f2bf(fmaxf(cy2, 0.f)) << 16) | f2bf(fmaxf(cx2, 0.f));
    *(unsigned*)(H + (size_t)row2 * 64 + fl * 2) = o2;
}

// ---- gather-sum + log_softmax -> out f32 [M][40]  (xw2 logical layout) ----
// Same two-pair structure; stride 80B; lanes fl<20 valid; butterfly per pair.
__global__ __launch_bounds__(256) void k_gs_lsm(
    const unsigned short* __restrict__ xw,   // [(n*8+r)][40] logical
    const int* __restrict__ ptr, const int* __restrict__ idx,
    const int* __restrict__ rel,
    float* __restrict__ out, int M) {
    int base = (blockIdx.x * 4 + (threadIdx.x >> 6)) * 4;
    if (base >= M) return;
    base = __builtin_amdgcn_readfirstlane(base);
    int lane = threadIdx.x & 63;
    int fl = lane & 31, eo = lane >> 5;
    int row1 = base + eo;
    int row2 = base + 2 + eo;
    bool okf = fl < 20;
    int flc = okf ? fl : 0;
    float cx1 = 0.f, cy1 = 0.f, cx2 = 0.f, cy2 = 0.f;
    bool fast4 = false;
    if (base + 3 < M) {
        int p0 = ptr[base], p1 = ptr[base + 1], p2 = ptr[base + 2];
        int p3 = ptr[base + 3], p4 = ptr[base + 4];
        if ((p1 - p0) == 16 && (p2 - p1) == 16 && (p3 - p2) == 16 && (p4 - p3) == 16) {
            fast4 = true;
            const int* ia = idx + p0; const int* ra = rel + p0;
            unsigned u1[16], u2[16];
#pragma unroll
            for (int t = 0; t < 16; ++t) {
                unsigned bA = ((unsigned)ia[t]      * 8u + (unsigned)ra[t])      * 80u;
                unsigned bB = ((unsigned)ia[16 + t] * 8u + (unsigned)ra[16 + t]) * 80u;
                unsigned b = eo ? bB : bA;
                u1[t] = *(const unsigned*)((const char*)xw + b + flc * 4);
            }
#pragma unroll
            for (int t = 0; t < 16; ++t) {
                unsigned bC = ((unsigned)ia[32 + t] * 8u + (unsigned)ra[32 + t]) * 80u;
                unsigned bD = ((unsigned)ia[48 + t] * 8u + (unsigned)ra[48 + t]) * 80u;
                unsigned b = eo ? bD : bC;
                u2[t] = *(const unsigned*)((const char*)xw + b + flc * 4);
            }
#pragma unroll
            for (int t = 0; t < 16; ++t) { cx1 += bflo(u1[t]); cy1 += bfhi(u1[t]); }
#pragma unroll
            for (int t = 0; t < 16; ++t) { cx2 += bflo(u2[t]); cy2 += bfhi(u2[t]); }
        }
    }
    if (!fast4) {
        if (row1 < M) {
            int ps = ptr[row1], deg = ptr[row1 + 1] - ps;
            for (int t = 0; t < deg; ++t) {
                unsigned b = ((unsigned)idx[ps + t] * 8u + (unsigned)rel[ps + t]) * 80u;
                unsigned u = *(const unsigned*)((const char*)xw + b + flc * 4);
                cx1 += bflo(u); cy1 += bfhi(u);
            }
        }
        if (row2 < M) {
            int ps = ptr[row2], deg = ptr[row2 + 1] - ps;
            for (int t = 0; t < deg; ++t) {
                unsigned b = ((unsigned)idx[ps + t] * 8u + (unsigned)rel[ps + t]) * 80u;
                unsigned u = *(const unsigned*)((const char*)xw + b + flc * 4);
                cx2 += bflo(u); cy2 += bfhi(u);
            }
        }
    }
    // pair-1 log-softmax (proven butterfly over 32 lanes, 2 vals in fl<20)
    {
        float mx = okf ? fmaxf(cx1, cy1) : -INFINITY;
#pragma unroll
        for (int m = 1; m < 32; m <<= 1) mx = fmaxf(mx, __shfl_xor(mx, m, 32));
        float s = okf ? (__expf(cx1 - mx) + __expf(cy1 - mx)) : 0.f;
#pragma unroll
        for (int m = 1; m < 32; m <<= 1) s += __shfl_xor(s, m, 32);
        float lse = mx + __logf(s);
        if (okf && row1 < M) {
            float2 o = {cx1 - lse, cy1 - lse};
            *(float2*)(out + (size_t)row1 * 40 + flc * 2) = o;
        }
    }
    // pair-2 log-softmax
    {
        float mx = okf ? fmaxf(cx2, cy2) : -INFINITY;
#pragma unroll
        for (int m = 1; m < 32; m <<= 1) mx = fmaxf(mx, __shfl_xor(mx, m, 32));
        float s = okf ? (__expf(cx2 - mx) + __expf(cy2 - mx)) : 0.f;
#pragma unroll
        for (int m = 1; m < 32; m <<= 1) s += __shfl_xor(s, m, 32);
        float lse = mx + __logf(s);
        if (okf && row2 < M) {
            float2 o = {cx2 - lse, cy2 - lse};
            *(float2*)(out + (size_t)row2 * 40 + flc * 2) = o;
        }
    }
}

extern "C" void kernel_launch(void* const* d_in, const int* in_sizes, int n_in,
                              void* d_out, int out_size, void* d_ws, size_t ws_size,
                              hipStream_t stream) {
    const float* x  = (const float*)d_in[0];
    const int* ptr  = (const int*)d_in[1];
    const int* idx  = (const int*)d_in[2];
    const int* rel  = (const int*)d_in[3];
    const float* W1 = (const float*)d_in[4];
    const float* W2 = (const float*)d_in[5];
    float* out = (float*)d_out;

    int N = in_sizes[1] - 1;                 // 75000
    int MP = (N + 255) & ~255;               // 75008

    char* ws = (char*)d_ws;
    unsigned short* BTf1 = (unsigned short*)ws;
    unsigned short* BTf2 = BTf1 + 32768;
    unsigned short* hbf  = BTf2 + 20480;                    // [MP][64]  = 9.6MB
    unsigned short* xw1b = hbf + (size_t)MP * 64;           // [MP][512] = 76.8MB
    unsigned short* xw2b = xw1b + (size_t)MP * 512;         // [MP][320] = 48MB (disjoint)
    // total ws use ~= 135MB

    k_packw<<<(32768 + 20480 + 255) / 256, 256, 0, stream>>>(W1, W2, BTf1, BTf2);

    int nblk = MP / 64;                      // 1172 blocks: 4 waves x 16 rows
    // layer 1: xw1 = cast(x) @ W1 (8 slabs, sigma-phys, B in 64KB LDS)
    k_xw<1, 8><<<nblk, 256, 0, stream>>>((const void*)x, BTf1, xw1b, N);
    k_gs_relu<<<MP / 16, 256, 0, stream>>>(xw1b, ptr, idx, rel, hbf, N, MP);
    // layer 2: xw2 = h @ W2 (5 slabs, logical cols, B in 40KB LDS)
    k_xw<0, 5><<<nblk, 256, 0, stream>>>((const void*)hbf, BTf2, xw2b, MP);
    k_gs_lsm<<<(N + 15) / 16, 256, 0, stream>>>(xw2b, ptr, idx, rel, out, N);
}

// Round 15
// 103.830 us; speedup vs baseline: 1.0818x; 1.0818x over previous
//
#include <hip/hip_runtime.h>
#include <hip/hip_bf16.h>

// RGCN CSR, two layers, MI355X.  Transform-then-gather, separate kernels.
//   xw1[n][512B] = int8(x @ W1flat, scale 16)   <- k_xw1 (bf16 MFMA, int8 out)
//   h[n][64]     = relu(gather_int8(xw1))/16    <- k_gs_relu (exact int accum)
//   xw2[n][320]  = h @ W2flat (bf16)            <- k_xw2
//   out[n][40]   = log_softmax(gather(xw2))     <- k_gs_lsm
// R15: xw1 quantized to int8 scale-16. R12/R14 proved the gathers are
// aggregate-line-bandwidth-bound (deeper per-wave batching = 0); so shrink
// the lines: int8 xw1 rows are 64B = ONE aligned cache line per edge
// (was 2), halving gather-1 L3 line traffic AND xw1 HBM write. Gather
// accumulates int8 in int32 (exact), one f32 convert+scale at the end.
// |xw1| < 7 << 127/16, err/elem ~0.02 -> absmax est +~0.5-0.9 (thr 2.52).
// Gather shape/index maps/sigma bookkeeping identical to proven R13.

typedef __attribute__((ext_vector_type(8))) short short8;
typedef __attribute__((ext_vector_type(4))) float floatx4;

static __device__ __forceinline__ unsigned short f2bf(float f) {
    unsigned u = __float_as_uint(f);
    u += 0x7FFFu + ((u >> 16) & 1u);      // RNE
    return (unsigned short)(u >> 16);
}
static __device__ __forceinline__ float bflo(unsigned u) { return __uint_as_float(u << 16); }
static __device__ __forceinline__ float bfhi(unsigned u) { return __uint_as_float(u & 0xffff0000u); }

// sigma: within-slab col interleave, involution on [0,64)
static __device__ __forceinline__ int sgm(int d) {
    return ((d & 12) << 2) | ((d & 48) >> 2) | (d & 3);
}

// ---- pack weights into fragment-linear BTf (bf16; MFMA operands) ----
// chunk = (cb*2+k0)*4+g (1KB each); within chunk, lane=lg*16+lr holds 8 shorts:
//   BTf[chunk*512 + lg*128 + lr*8 + s] = B[cb*64+g*16+lr][k0*32+lg*8+s]
// Layer1: B[j][d] = W1[r][d][f], j=r*64+f.       (8 slabs, 32768 shorts)
// Layer2: B[j][d] = W2[r][sgm(d)][f], j=r*40+f.  (5 slabs, 20480 shorts)
__global__ void k_packw(const float* __restrict__ W1, const float* __restrict__ W2,
                        unsigned short* __restrict__ BTf1, unsigned short* __restrict__ BTf2) {
    int i = blockIdx.x * 256 + threadIdx.x;
    if (i < 32768) {
        int chunk = i >> 9, w = i & 511;
        int cb = chunk >> 3, k0 = (chunk >> 2) & 1, g = chunk & 3;
        int lg = w >> 7, lr = (w >> 3) & 15, s = w & 7;
        int j = cb * 64 + g * 16 + lr;
        int d = k0 * 32 + lg * 8 + s;
        int r = j >> 6, f = j & 63;
        BTf1[i] = f2bf(W1[r * 4096 + d * 64 + f]);
    } else if (i < 32768 + 20480) {
        int ii = i - 32768;
        int chunk = ii >> 9, w = ii & 511;
        int cb = chunk >> 3, k0 = (chunk >> 2) & 1, g = chunk & 3;
        int lg = w >> 7, lr = (w >> 3) & 15, s = w & 7;
        int j = cb * 64 + g * 16 + lr;                 // < 320
        int d = k0 * 32 + lg * 8 + s;
        int r = j / 40, f = j - r * 40;
        BTf2[ii] = f2bf(W2[r * 2560 + sgm(d) * 40 + f]);
    }
}

// ---- layer-1 GEMM: xw1[MP][512B] = int8( cast(x) @ W1^T · 16 )  (B in LDS) ----
// sigma-phys int8 output: row n, slab cb, phys col lg*16+g*4+i -> byte
// n*512 + cb*64 + lg*16 + g*4 + i; one 16B store per slab per thread.
__global__ __launch_bounds__(256) void k_xw1(
    const float* __restrict__ Af, const unsigned short* __restrict__ BTf,
    char* __restrict__ xw, int M) {
    __shared__ short Bs[8 * 4096];            // 64KB
#pragma unroll
    for (int off = 0; off < 8 * 4096; off += 2048)
        *(short8*)(Bs + off + threadIdx.x * 8) =
            *(const short8*)((const short*)BTf + off + threadIdx.x * 8);

    int wave = threadIdx.x >> 6, lane = threadIdx.x & 63;
    int lr = lane & 15, lg = lane >> 4;
    int rowbase = (blockIdx.x * 4 + wave) * 16;
    int row = rowbase + lr;

    short8 af[2];                             // fused f32->bf16 cast, read once
#pragma unroll
    for (int k0 = 0; k0 < 2; ++k0) {
        int koff = k0 * 32 + lg * 8;
        float4 v0 = {0, 0, 0, 0}, v1 = {0, 0, 0, 0};
        if (row < M) {
            v0 = *(const float4*)(Af + (size_t)row * 64 + koff);
            v1 = *(const float4*)(Af + (size_t)row * 64 + koff + 4);
        }
        short8 t;
        t[0] = (short)f2bf(v0.x); t[1] = (short)f2bf(v0.y);
        t[2] = (short)f2bf(v0.z); t[3] = (short)f2bf(v0.w);
        t[4] = (short)f2bf(v1.x); t[5] = (short)f2bf(v1.y);
        t[6] = (short)f2bf(v1.z); t[7] = (short)f2bf(v1.w);
        af[k0] = t;
    }

    __syncthreads();                          // LDS B ready

#pragma unroll
    for (int cb = 0; cb < 8; ++cb) {
        floatx4 acc[4] = {};
#pragma unroll
        for (int k0 = 0; k0 < 2; ++k0)
#pragma unroll
            for (int g = 0; g < 4; ++g) {
                short8 b = *(const short8*)(Bs + ((cb * 2 + k0) * 4 + g) * 512 + lane * 8);
                acc[g] = __builtin_amdgcn_mfma_f32_16x16x32_bf16(b, af[k0], acc[g], 0, 0, 0);
            }
        // quantize 16 values to int8 (scale 16, RNE, clamp) and pack 16B
        unsigned dw[4];
#pragma unroll
        for (int g = 0; g < 4; ++g) {
            unsigned d = 0;
#pragma unroll
            for (int i = 0; i < 4; ++i) {
                int q = (int)rintf(acc[g][i] * 16.0f);
                q = q > 127 ? 127 : (q < -127 ? -127 : q);
                d |= ((unsigned)q & 255u) << (8 * i);
            }
            dw[g] = d;
        }
        int4 o = {(int)dw[0], (int)dw[1], (int)dw[2], (int)dw[3]};
        *(int4*)(xw + (size_t)row * 512 + cb * 64 + lg * 16) = o;
    }
}

// ---- gather-sum(int8) + relu -> h bf16 [MP][64] (phys layout); zero pad rows ----
// 2 rows/wave (proven shape): half-wave eo owns one row; lane loads ushort
// (2 int8 feats); exact int32 accumulation; one scale+relu at the end.
__global__ __launch_bounds__(256) void k_gs_relu(
    const char* __restrict__ xw,             // [(n*8+r)][64B] int8 (scale 1/16)
    const int* __restrict__ ptr, const int* __restrict__ idx,
    const int* __restrict__ rel,
    unsigned short* __restrict__ H, int M, int MP) {
    int rowA = (blockIdx.x * 4 + (threadIdx.x >> 6)) * 2;
    if (rowA >= MP) return;
    rowA = __builtin_amdgcn_readfirstlane(rowA);
    int lane = threadIdx.x & 63;
    int fl = lane & 31, eo = lane >> 5;
    int rowB = rowA + 1;
    int myrow = eo ? rowB : rowA;
    if (rowA >= M) {                          // pad pair -> zeros
        *(unsigned*)(H + (size_t)myrow * 64 + fl * 2) = 0;
        return;
    }
    int ix = 0, iy = 0;
    bool both = (rowB < M);
    int p0 = ptr[rowA], p1 = ptr[rowA + 1];
    int p2 = both ? ptr[rowA + 2] : p1;
    if (both && (p1 - p0 == 16) && (p2 - p1 == 16)) {
        const int* ia = idx + p0; const int* ra_ = rel + p0;   // scalar (uniform)
        const int* ib = idx + p1; const int* rb_ = rel + p1;
        unsigned short u[16];
#pragma unroll
        for (int t = 0; t < 16; ++t) {
            unsigned bA = ((unsigned)ia[t] * 8u + (unsigned)ra_[t]) * 64u;
            unsigned bB = ((unsigned)ib[t] * 8u + (unsigned)rb_[t]) * 64u;
            unsigned b = eo ? bB : bA;
            u[t] = *(const unsigned short*)(xw + b + fl * 2);
        }
#pragma unroll
        for (int t = 0; t < 16; ++t) {
            ix += (int)(signed char)(u[t] & 0xff);
            iy += (int)(signed char)(u[t] >> 8);
        }
    } else {
        int ps = 0, deg = 0;
        if (myrow < M) { ps = ptr[myrow]; deg = ptr[myrow + 1] - ps; }
        for (int t = 0; t < deg; ++t) {
            unsigned b = ((unsigned)idx[ps + t] * 8u + (unsigned)rel[ps + t]) * 64u;
            unsigned short u = *(const unsigned short*)(xw + b + fl * 2);
            ix += (int)(signed char)(u & 0xff);
            iy += (int)(signed char)(u >> 8);
        }
    }
    float cx = (float)ix * 0.0625f, cy = (float)iy * 0.0625f;
    unsigned o = ((unsigned)f2bf(fmaxf(cy, 0.f)) << 16) | f2bf(fmaxf(cx, 0.f));
    *(unsigned*)(H + (size_t)myrow * 64 + fl * 2) = o;
}

// ---- layer-2 GEMM: xw2[MP][320] = h @ W2^T  (bf16, B in LDS, logical cols) ----
__global__ __launch_bounds__(256) void k_xw2(
    const unsigned short* __restrict__ Ab, const unsigned short* __restrict__ BTf,
    unsigned short* __restrict__ xw, int M) {
    __shared__ short Bs[5 * 4096];            // 40KB
#pragma unroll
    for (int off = 0; off < 5 * 4096; off += 2048)
        *(short8*)(Bs + off + threadIdx.x * 8) =
            *(const short8*)((const short*)BTf + off + threadIdx.x * 8);

    int wave = threadIdx.x >> 6, lane = threadIdx.x & 63;
    int lr = lane & 15, lg = lane >> 4;
    int rowbase = (blockIdx.x * 4 + wave) * 16;
    int row = rowbase + lr;

    short8 af[2];
#pragma unroll
    for (int k0 = 0; k0 < 2; ++k0)
        af[k0] = *(const short8*)(Ab + (size_t)row * 64 + k0 * 32 + lg * 8);

    __syncthreads();

#pragma unroll
    for (int cb = 0; cb < 5; ++cb) {
        int col0 = cb * 64;
        floatx4 acc[4] = {};
#pragma unroll
        for (int k0 = 0; k0 < 2; ++k0)
#pragma unroll
            for (int g = 0; g < 4; ++g) {
                short8 b = *(const short8*)(Bs + ((cb * 2 + k0) * 4 + g) * 512 + lane * 8);
                acc[g] = __builtin_amdgcn_mfma_f32_16x16x32_bf16(b, af[k0], acc[g], 0, 0, 0);
            }
        // logical store: acc[g][i] = col col0 + g*16 + lg*4 + i of row
#pragma unroll
        for (int g = 0; g < 4; ++g) {
            unsigned lo = ((unsigned)f2bf(acc[g][1]) << 16) | f2bf(acc[g][0]);
            unsigned hi = ((unsigned)f2bf(acc[g][3]) << 16) | f2bf(acc[g][2]);
            uint2 o = {lo, hi};
            *(uint2*)(xw + (size_t)row * 320 + col0 + g * 16 + lg * 4) = o;
        }
    }
}

// ---- gather-sum + log_softmax -> out f32 [M][40]  (xw2 bf16 logical) ----
__global__ __launch_bounds__(256) void k_gs_lsm(
    const unsigned short* __restrict__ xw,   // [(n*8+r)][40] logical
    const int* __restrict__ ptr, const int* __restrict__ idx,
    const int* __restrict__ rel,
    float* __restrict__ out, int M) {
    int rowA = (blockIdx.x * 4 + (threadIdx.x >> 6)) * 2;
    if (rowA >= M) return;
    rowA = __builtin_amdgcn_readfirstlane(rowA);
    int lane = threadIdx.x & 63;
    int fl = lane & 31, eo = lane >> 5;
    int rowB = rowA + 1;
    int myrow = eo ? rowB : rowA;
    bool okf = fl < 20;
    int flc = okf ? fl : 0;
    float cx = 0.f, cy = 0.f;
    bool both = (rowB < M);
    int p0 = ptr[rowA], p1 = ptr[rowA + 1];
    int p2 = both ? ptr[rowA + 2] : p1;
    if (both && (p1 - p0 == 16) && (p2 - p1 == 16)) {
        const int* ia = idx + p0; const int* ra_ = rel + p0;
        const int* ib = idx + p1; const int* rb_ = rel + p1;
        unsigned u[16];
#pragma unroll
        for (int t = 0; t < 16; ++t) {
            unsigned bA = ((unsigned)ia[t] * 8u + (unsigned)ra_[t]) * 80u;
            unsigned bB = ((unsigned)ib[t] * 8u + (unsigned)rb_[t]) * 80u;
            unsigned b = eo ? bB : bA;
            u[t] = *(const unsigned*)((const char*)xw + b + flc * 4);
        }
#pragma unroll
        for (int t = 0; t < 16; ++t) { cx += bflo(u[t]); cy += bfhi(u[t]); }
    } else {
        int ps = 0, deg = 0;
        if (myrow < M) { ps = ptr[myrow]; deg = ptr[myrow + 1] - ps; }
        for (int t = 0; t < deg; ++t) {
            unsigned b = ((unsigned)idx[ps + t] * 8u + (unsigned)rel[ps + t]) * 80u;
            unsigned u = *(const unsigned*)((const char*)xw + b + flc * 4);
            cx += bflo(u); cy += bfhi(u);
        }
    }
    float mx = okf ? fmaxf(cx, cy) : -INFINITY;
#pragma unroll
    for (int m = 1; m < 32; m <<= 1) mx = fmaxf(mx, __shfl_xor(mx, m, 32));
    float s = okf ? (__expf(cx - mx) + __expf(cy - mx)) : 0.f;
#pragma unroll
    for (int m = 1; m < 32; m <<= 1) s += __shfl_xor(s, m, 32);
    float lse = mx + __logf(s);
    if (okf && myrow < M) {
        float2 o = {cx - lse, cy - lse};
        *(float2*)(out + (size_t)myrow * 40 + flc * 2) = o;
    }
}

extern "C" void kernel_launch(void* const* d_in, const int* in_sizes, int n_in,
                              void* d_out, int out_size, void* d_ws, size_t ws_size,
                              hipStream_t stream) {
    const float* x  = (const float*)d_in[0];
    const int* ptr  = (const int*)d_in[1];
    const int* idx  = (const int*)d_in[2];
    const int* rel  = (const int*)d_in[3];
    const float* W1 = (const float*)d_in[4];
    const float* W2 = (const float*)d_in[5];
    float* out = (float*)d_out;

    int N = in_sizes[1] - 1;                 // 75000
    int MP = (N + 255) & ~255;               // 75008

    char* ws = (char*)d_ws;
    unsigned short* BTf1 = (unsigned short*)ws;
    unsigned short* BTf2 = BTf1 + 32768;
    unsigned short* hbf  = BTf2 + 20480;                    // [MP][64] bf16 = 9.6MB
    char*           xw1b = (char*)(hbf + (size_t)MP * 64);  // [MP][512] int8 = 38.4MB
    unsigned short* xw2b = (unsigned short*)(xw1b + (size_t)MP * 512);  // [MP][320] bf16 = 48MB
    // total ws use ~= 96.2MB; all regions disjoint

    k_packw<<<(32768 + 20480 + 255) / 256, 256, 0, stream>>>(W1, W2, BTf1, BTf2);

    int nblk = MP / 64;                      // 1172 blocks: 4 waves x 16 rows
    // layer 1: xw1 = int8(cast(x) @ W1, scale 16) (8 slabs, sigma-phys, B in 64KB LDS)
    k_xw1<<<nblk, 256, 0, stream>>>(x, BTf1, xw1b, N);
    k_gs_relu<<<MP / 8, 256, 0, stream>>>(xw1b, ptr, idx, rel, hbf, N, MP);
    // layer 2: xw2 = h @ W2 (bf16, 5 slabs, logical cols, B in 40KB LDS)
    k_xw2<<<nblk, 256, 0, stream>>>(hbf, BTf2, xw2b, MP);
    k_gs_lsm<<<(N + 7) / 8, 256, 0, stream>>>(xw2b, ptr, idx, rel, out, N);
}